// Round 5
// baseline (148.236 us; speedup 1.0000x reference)
//
#include <hip/hip_runtime.h>
#include <cstdint>

typedef __attribute__((ext_vector_type(8))) short bf16x8;    // 8 bf16 = 4 VGPRs
typedef __attribute__((ext_vector_type(16))) float f32x16;   // 32x32 MFMA C/D
typedef __attribute__((ext_vector_type(4))) float f4;
typedef __attribute__((ext_vector_type(8))) unsigned short u16x8;
typedef unsigned short u16;

// JOURNAL:
// R6: __launch_bounds__(256,6) forced VGPR 72->40, scratch spills (+36MB traffic).
// R7: device-scope __threadfence() reduction inside gemm3 = L2 writeback storms.
// R8: (256,8) neutral; residency saturated ~4 blocks/CU.
// R9: 32x32x16 MFMA beats 16x16x32 (-5us). BEST = 148.4us.
// R10: 256x64/KSPLIT=8 neutral -- confounded (intensity 44->52 AND 2x partials).
// R11: part aliased cast region -> GPU abort. R12: dedicated region. 142.7us.
// R13 FAILED: TN 64->128 => 47.2us gemm12. Occupancy 12%, MfmaUtil 15%.
// R14 PARTIAL: 2-phase dbuf + counted vmcnt(8): 147->139.7. Both GEMMs ~41us.
// R15: infra fail (no data). R16: XCD supertile swizzle: 139.7->137.7 (+2us,
//      ~noise). L2-locality theory falsified as the main wall. ACCOUNTING:
//      kernels sum ~95us; ~42us of dur is the harness 256MiB ws re-poison
//      (fillBuffer @6.3TB/s) inside the timed window — fixed cost.
// R17 (this round): gemm3 -> m97-parity config (single-variable): KSPLIT=8
//      (grid 1024 = 4.0 blocks/CU), single-buffer 32KB LDS + syncthreads
//      drain (m97's proven 874-912 TF structure), z-slice = XCD (A panel
//      4MB = L2). Partials 33.6MB, reduce4 z<8 (+3us). gemm12 untouched.
//      Predict gemm3 ~41->~22-25us, total ->~120. If gemm3 >=35us: short-K
//      caps m97 structure -> 256^2 8-phase port next.

__device__ __forceinline__ u16 f2bf(float f) {
  uint32_t u = __builtin_bit_cast(uint32_t, f);
  u += 0x7fffu + ((u >> 16) & 1u);          // round-to-nearest-even
  return (u16)(u >> 16);
}

__device__ __forceinline__ float bf2f(u16 h) {
  return __builtin_bit_cast(float, (uint32_t)h << 16);
}

__device__ __forceinline__ void async_cp16(const void* g, void* l) {
  __builtin_amdgcn_global_load_lds(
      (const __attribute__((address_space(1))) uint32_t*)g,
      (__attribute__((address_space(3))) uint32_t*)l, 16, 0, 0);
}

// cast x | features | prototypes -> contiguous bf16 region in ws (8 elem/thread)
__global__ __launch_bounds__(256) void cast3(
    const float* __restrict__ x, const float* __restrict__ f,
    const float* __restrict__ p, u16* __restrict__ dst,
    int n1, int n2, int n3) {
  int i = (blockIdx.x * 256 + threadIdx.x) * 8;
  const float* src;
  int local;
  if (i < n1) { src = x; local = i; }
  else if (i < n1 + n2) { src = f; local = i - n1; }
  else if (i < n1 + n2 + n3) { src = p; local = i - n1 - n2; }
  else return;
  f4 a = *(const f4*)(src + local);
  f4 b = *(const f4*)(src + local + 4);
  u16x8 o;
  o[0] = f2bf(a.x); o[1] = f2bf(a.y); o[2] = f2bf(a.z); o[3] = f2bf(a.w);
  o[4] = f2bf(b.x); o[5] = f2bf(b.y); o[6] = f2bf(b.z); o[7] = f2bf(b.w);
  *(u16x8*)(dst + i) = o;
}

// ---- shared staging/compute pieces (TM=128, TN=128, BK=64) ----
// C += A @ B^T with 32x32x16 MFMA. 16B-chunk XOR swizzle (0 bank conflicts).
// Wave grid 2x2: wave covers 64x64 = 2x2 acc tiles of 32x32.

__device__ __forceinline__ void stage_tile(
    const u16* __restrict__ A, const u16* __restrict__ B, int K,
    int k0, int tid, u16* L) {
  constexpr int TM = 128, TN = 128;
  const int wave = tid >> 6;
  #pragma unroll
  for (int it = 0; it < TM / 32; ++it) {
    int c = it * 256 + tid;            // chunk index = LDS position
    int row = c >> 3, pc = c & 7;
    int gc = pc ^ (row & 7);           // which global 16B chunk lands here
    async_cp16(A + (size_t)row * K + (k0 + gc * 8),
               &L[(it * 256 + wave * 64) * 8]);
  }
  #pragma unroll
  for (int it = 0; it < TN / 32; ++it) {
    int c = it * 256 + tid;
    int row = c >> 3, pc = c & 7;
    int gc = pc ^ (row & 7);
    async_cp16(B + (size_t)row * K + (k0 + gc * 8),
               &L[TM * 64 + (it * 256 + wave * 64) * 8]);
  }
}

__device__ __forceinline__ void compute_tile(
    const u16* L, int lane, int wrow, int wcol, f32x16 (&acc)[2][2]) {
  constexpr int TM = 128;
  #pragma unroll
  for (int s = 0; s < 4; ++s) {        // 4 k-steps of K=16
    const int h = s * 2 + (lane >> 5); // 16B chunk along K this lane needs
    bf16x8 bfr[2], afr[2];
    #pragma unroll
    for (int j = 0; j < 2; ++j) {
      const int rb = wcol * 64 + j * 32 + (lane & 31);
      bfr[j] = *(const bf16x8*)&L[TM * 64 + (rb * 8 + (h ^ (rb & 7))) * 8];
    }
    #pragma unroll
    for (int i = 0; i < 2; ++i) {
      const int ra = wrow * 64 + i * 32 + (lane & 31);
      afr[i] = *(const bf16x8*)&L[(ra * 8 + (h ^ (ra & 7))) * 8];
    }
    #pragma unroll
    for (int i = 0; i < 2; ++i)
      #pragma unroll
      for (int j = 0; j < 2; ++j)
        acc[i][j] = __builtin_amdgcn_mfma_f32_32x32x16_bf16(
            afr[i], bfr[j], acc[i][j], 0, 0, 0);
  }
}

// 2-phase double-buffered mainloop (64KB LDS) — used by gemm12.
__device__ __forceinline__ void mainloop(
    const u16* __restrict__ A, const u16* __restrict__ B, int K,
    int kbeg, int kend, int tid, u16* lds, f32x16 (&acc)[2][2]) {
  constexpr int BK = 64;
  constexpr int BUF = 16384;           // u16 per LDS buffer (32 KiB)
  const int lane = tid & 63;
  const int wave = tid >> 6;
  const int wrow = wave >> 1, wcol = wave & 1;

  stage_tile(A, B, K, kbeg, tid, lds); // prologue: tile 0 -> buf 0
  int cur = 0;
  for (int k0 = kbeg; k0 < kend; k0 += BK) {
    if (k0 + BK < kend) {
      stage_tile(A, B, K, k0 + BK, tid, lds + (cur ^ 1) * BUF);
      asm volatile("s_waitcnt vmcnt(8)" ::: "memory");
    } else {
      asm volatile("s_waitcnt vmcnt(0)" ::: "memory");
    }
    __builtin_amdgcn_s_barrier();      // all waves: current buffer complete
    compute_tile(lds + cur * BUF, lane, wrow, wcol, acc);
    __builtin_amdgcn_s_barrier();      // all waves done reading before next
    cur ^= 1;                          // iter overwrites this buffer
  }
}

// Single-buffer m97-style mainloop (32KB LDS, syncthreads drain) — gemm3.
// Latency hiding comes from 4 blocks/CU cross-block overlap (m114/m97).
__device__ __forceinline__ void mainloop_sb(
    const u16* __restrict__ A, const u16* __restrict__ B, int K,
    int kbeg, int kend, int tid, u16* lds, f32x16 (&acc)[2][2]) {
  constexpr int BK = 64;
  const int lane = tid & 63;
  const int wave = tid >> 6;
  const int wrow = wave >> 1, wcol = wave & 1;

  for (int k0 = kbeg; k0 < kend; k0 += BK) {
    stage_tile(A, B, K, k0, tid, lds);
    __syncthreads();                   // vmcnt(0) drain + barrier
    compute_tile(lds, lane, wrow, wcol, acc);
    __syncthreads();                   // done reading before next overwrite
  }
}

// 32x32 C/D mapping (m74/m101 verified): col = lane&31,
// row = (reg&3) + 8*(reg>>2) + 4*(lane>>5), reg in [0,16).

// ---- GEMM1+GEMM2 merged: [x; proto](4608 x 1024) @ feat^T, tile 128x128 ----
// 1D grid 576; XCD-supertile decode: XCD k = bid%8 owns a 9x8 tile panel
// (kx=k%4, ky=k/4): x = kx*9 + slot/8, y = ky*8 + slot%8, slot = bid/8.
// x-rows  -> Acat[row, f]=xf*relu(xf), Acat[row, 2048+f]=1-relu(xf)
// p-rows  -> Bcat[row, f]=th*c-al*(1-pres), Bcat[row, 2048+f]=-be*c
// Epilogue: LDS transpose (stride 136 u16 = 17x16B) -> 128B-coalesced stores.
__global__ __launch_bounds__(256) void gemm12(
    const u16* __restrict__ xb, const u16* __restrict__ pb,
    const u16* __restrict__ fb, u16* __restrict__ Acat, u16* __restrict__ Bcat,
    const float* __restrict__ alpha, const float* __restrict__ beta,
    const float* __restrict__ theta) {
  constexpr int TM = 128, K = 1024, N = 2048;
  constexpr int TSTRIDE = 136;           // u16; 272B rows = 17*16B aligned
  __shared__ u16 lds[32768];             // 64 KiB: 2 mainloop bufs; transpose reuses

  const int tid = threadIdx.x;
  const int lane = tid & 63;
  const int wave = tid >> 6;
  const int wrow = wave >> 1, wcol = wave & 1;

  // XCD-aware supertile decode (bijective: 576 = 8 * 72, panels 9x8)
  const int bid = blockIdx.x;
  const int xcd = bid & 7, slot = bid >> 3;        // xcd 0..7, slot 0..71
  const int xt = (xcd & 3) * 9 + (slot >> 3);      // 0..35
  const int yt = (xcd >> 2) * 8 + (slot & 7);      // 0..15

  const int bm_all = xt * TM;
  const int bn = yt * 128;
  const bool is_x = bm_all < 4096;       // block purely x or proto (4096%128==0)
  const u16* A = is_x ? xb + (size_t)bm_all * K : pb + (size_t)(bm_all - 4096) * K;
  const u16* B = fb + (size_t)bn * K;

  f32x16 acc[2][2] = {};
  mainloop(A, B, K, 0, K, tid, lds, acc);

  float th = 0.f, al = 0.f, be = 0.f;
  if (!is_x) { th = theta[0]; al = alpha[0]; be = beta[0]; }
  u16* dst = is_x ? Acat : Bcat;
  const int rowbase = is_x ? bm_all : bm_all - 4096;
  const int rquad = 4 * (lane >> 5);

  #pragma unroll
  for (int half = 0; half < 2; ++half) {
    __syncthreads();   // protect lds reuse (mainloop end / previous half's reads)
    #pragma unroll
    for (int i = 0; i < 2; ++i) {
      #pragma unroll
      for (int j = 0; j < 2; ++j) {
        const int cl = wcol * 64 + j * 32 + (lane & 31);
        #pragma unroll
        for (int r = 0; r < 16; ++r) {
          const int rl = wrow * 64 + i * 32 + (r & 3) + 8 * (r >> 2) + rquad;
          float v = acc[i][j][r];
          float pres = v > 0.f ? v : 0.f;
          float o;
          if (is_x) o = half == 0 ? v * pres : 1.f - pres;
          else {
            float cc = v * pres;
            o = half == 0 ? th * cc - al * (1.f - pres) : -be * cc;
          }
          lds[rl * TSTRIDE + cl] = f2bf(o);
        }
      }
    }
    __syncthreads();
    #pragma unroll
    for (int v = 0; v < 8; ++v) {
      const int rl = v * 16 + (tid >> 4);
      const int c8 = (tid & 15) * 8;
      u16x8 vec = *(const u16x8*)&lds[rl * TSTRIDE + c8];
      *(u16x8*)&dst[(size_t)(rowbase + rl) * (2 * N) + bn + c8 + half * N] = vec;
    }
  }
}

// ---- GEMM3 split-K: part[z] = Acat @ Bcat^T partial (bf16), tile 128x128 ----
// KSPLIT=8, 1D grid 1024 = 4.0 blocks/CU (m97-parity residency), single-buffer
// 32KB LDS. XCD decode: z-slice = XCD (bid%8): per-XCD A working set =
// 4096x512x2B = 4MB = L2; B = 0.5MB. slot = bid/8: bxt = slot%32, byt = slot/32.
// Partials bf16 thread-linear: tile = 16384 u16; chunk q = i*4 + j*2 + h.
__global__ __launch_bounds__(256) void gemm3(
    const u16* __restrict__ Acat, const u16* __restrict__ Bcat,
    u16* __restrict__ part) {
  constexpr int TM = 128, TN = 128, K = 4096, KSPLIT = 8;
  __shared__ u16 lds[16384];             // 32 KiB single buffer

  const int tid = threadIdx.x;

  // XCD-aware decode (bijective: 1024 = 8 * 128)
  const int bid = blockIdx.x;
  const int bz = bid & 7;                          // z-slice = XCD
  const int slot = bid >> 3;                       // 0..127
  const int bxt = slot & 31;                       // 0..31
  const int byt = slot >> 5;                       // 0..3

  const int bm = bxt * TM;
  const int bn = byt * TN;
  const int kbeg = bz * (K / KSPLIT);
  const int kend = kbeg + (K / KSPLIT);

  f32x16 acc[2][2] = {};
  mainloop_sb(Acat + (size_t)bm * K, Bcat + (size_t)bn * K, K, kbeg, kend,
              tid, lds, acc);

  const size_t pbase = ((size_t)bz * 128 + byt * 32 + bxt) * 16384;
  #pragma unroll
  for (int i = 0; i < 2; ++i)
    #pragma unroll
    for (int j = 0; j < 2; ++j)
      #pragma unroll
      for (int h = 0; h < 2; ++h) {
        u16x8 o;
        #pragma unroll
        for (int e = 0; e < 8; ++e) o[e] = f2bf(acc[i][j][h * 8 + e]);
        *(u16x8*)&part[pbase + (size_t)(i * 4 + j * 2 + h) * 2048 + tid * 8] = o;
      }
}

// ---- reduce bf16 partials over z=0..8, scatter fp32 to out ----
// 1024 blocks: one q-chunk per block (tileId = bx>>3, q = bx&7). Mirrors
// gemm3 map: q = i*4+j*2+h; reg = h*8+e; row = bm + wrow*64 + i*32 +
// (reg&3)+8*(reg>>2)+4*(lane>>5); col = bn + wcol*64 + j*32 + (lane&31).
__global__ __launch_bounds__(256) void reduce4(
    const u16* __restrict__ part, float* __restrict__ out) {
  constexpr int N = 512;
  const int tid = threadIdx.x;
  const int lane = tid & 63;
  const int wave = tid >> 6;
  const int wrow = wave >> 1, wcol = wave & 1;
  const int tileId = blockIdx.x >> 3;      // 0..127 = by*32+bx
  const int q = blockIdx.x & 7;
  const int bm = (tileId & 31) * 128;
  const int bn = (tileId >> 5) * 128;

  float v[8] = {};
  #pragma unroll
  for (int z = 0; z < 8; ++z) {
    u16x8 u = *(const u16x8*)&part[((size_t)z * 128 + tileId) * 16384 +
                                   (size_t)q * 2048 + tid * 8];
    #pragma unroll
    for (int e = 0; e < 8; ++e) v[e] += bf2f(u[e]);
  }
  const int i = q >> 2, j = (q >> 1) & 1, h = q & 1;
  const int gc = bn + wcol * 64 + j * 32 + (lane & 31);
  const int grb = bm + wrow * 64 + i * 32 + 4 * (lane >> 5);
  #pragma unroll
  for (int e = 0; e < 8; ++e) {
    const int reg = h * 8 + e;
    out[(size_t)(grb + (reg & 3) + 8 * (reg >> 2)) * N + gc] = v[e];
  }
}

extern "C" void kernel_launch(void* const* d_in, const int* in_sizes, int n_in,
                              void* d_out, int out_size, void* d_ws, size_t ws_size,
                              hipStream_t stream) {
  const float* x     = (const float*)d_in[0];
  const float* feat  = (const float*)d_in[1];
  const float* proto = (const float*)d_in[2];
  const float* alpha = (const float*)d_in[3];
  const float* beta  = (const float*)d_in[4];
  const float* theta = (const float*)d_in[5];
  float* out = (float*)d_out;

  constexpr int Bb = 4096, Ii = 1024, Pp = 512, Ff = 2048;

  // ws layout (NO aliasing — R12 defensive change): casts | Acat | Bcat | part.
  // Total ~105 MB of the 256 MiB workspace.
  char* ws = (char*)d_ws;
  u16* xb   = (u16*)ws;                               // 8.4 MB
  u16* fb   = xb + (size_t)Bb * Ii;                   // 4.2 MB
  u16* pb   = fb + (size_t)Ff * Ii;                   // 1.0 MB
  size_t r0 = 33554432;                               // 32 MiB region0 (casts)
  u16* Acat = (u16*)(ws + r0);                        // 33.6 MB
  u16* Bcat = Acat + (size_t)Bb * 2 * Ff;             // 4.2 MB
  u16* part = Bcat + (size_t)Pp * 2 * Ff;             // 33.6 MB (KSPLIT=8)

  const int n1 = Bb * Ii, n2 = Ff * Ii, n3 = Pp * Ii;
  cast3<<<((n1 + n2 + n3) / 8 + 255) / 256, 256, 0, stream>>>(
      x, feat, proto, xb, n1, n2, n3);

  // merged GEMM1+GEMM2: M=4608, N=2048; 1D grid 576 with XCD supertile decode
  gemm12<<<576, 256, 0, stream>>>(xb, pb, fb, Acat, Bcat, alpha, beta, theta);

  // GEMM3: 4096x512, K=4096 split 8 ways; 1D grid 1024, z-slice = XCD
  gemm3<<<1024, 256, 0, stream>>>(Acat, Bcat, part);

  // reduce z=0..8 -> out (8 blocks per tile, one q-chunk each)
  reduce4<<<1024, 256, 0, stream>>>(part, out);
}

// Round 6
// 138.222 us; speedup vs baseline: 1.0725x; 1.0725x over previous
//
#include <hip/hip_runtime.h>
#include <cstdint>

typedef __attribute__((ext_vector_type(8))) short bf16x8;    // 8 bf16 = 4 VGPRs
typedef __attribute__((ext_vector_type(16))) float f32x16;   // 32x32 MFMA C/D
typedef __attribute__((ext_vector_type(4))) float f4;
typedef __attribute__((ext_vector_type(8))) unsigned short u16x8;
typedef unsigned short u16;

// JOURNAL:
// R6: __launch_bounds__(256,6) forced VGPR 72->40, scratch spills (+36MB traffic).
// R7: device-scope __threadfence() gemm3 reduction = L2 writeback storms.
// R9: 32x32x16 MFMA beats 16x16x32 (-5us).
// R10: 256x64/KSPLIT=8 neutral (confounded). R11/R12: ws aliasing abort -> fixed.
// R13 FAILED: 128^2 tile alone: 47.2us gemm12 (Occ 12%, MfmaUtil 15%).
// R14 PARTIAL: 2-phase dbuf + counted vmcnt(8): 147->139.7. GEMMs ~41us each.
// R16: XCD supertile swizzle: +2us (~noise). L2-locality not the wall.
//      ACCOUNTING: kernels ~95us; ~42us = harness 256MiB ws re-poison (fixed).
// R17 FAILED: gemm3 m97-parity (KSPLIT=8, single-buf, syncthreads, 4 blk/CU):
//      148.2us (gemm3 ~48). Falsifies "residency is the gap": syncthreads-drain
//      serializes stage->compute; same-phase blocks don't skew at 8 iters.
//      m102 curve agrees (m97 structure = 320 TF at 2048-class shapes).
//      => keep 2-phase dbuf, raise per-K-step intensity instead.
// R18 (this round): gemm3 -> 256^2 2-phase dbuf (m230/m248 measured 655-682 TF
//      refcheck'd for exactly this config). 8 waves/512 thr, acc[4][2],
//      128KB LDS, 32 MFMA/wave/K-step (131 FLOP/staged-B). KSPLIT=8, grid 256
//      = 1 blk/CU; z=XCD (A panel 4MB=L2). vmcnt(8) unchanged (8 loads/thread).
//      reduce4 -> 512x512. gemm12 untouched. Predict gemm3 ~41->26-29us,
//      total ->~122-127. If gemm3 >=35us: pivot to 8-phase schedule.

__device__ __forceinline__ u16 f2bf(float f) {
  uint32_t u = __builtin_bit_cast(uint32_t, f);
  u += 0x7fffu + ((u >> 16) & 1u);          // round-to-nearest-even
  return (u16)(u >> 16);
}

__device__ __forceinline__ float bf2f(u16 h) {
  return __builtin_bit_cast(float, (uint32_t)h << 16);
}

__device__ __forceinline__ void async_cp16(const void* g, void* l) {
  __builtin_amdgcn_global_load_lds(
      (const __attribute__((address_space(1))) uint32_t*)g,
      (__attribute__((address_space(3))) uint32_t*)l, 16, 0, 0);
}

// cast x | features | prototypes -> contiguous bf16 region in ws (8 elem/thread)
__global__ __launch_bounds__(256) void cast3(
    const float* __restrict__ x, const float* __restrict__ f,
    const float* __restrict__ p, u16* __restrict__ dst,
    int n1, int n2, int n3) {
  int i = (blockIdx.x * 256 + threadIdx.x) * 8;
  const float* src;
  int local;
  if (i < n1) { src = x; local = i; }
  else if (i < n1 + n2) { src = f; local = i - n1; }
  else if (i < n1 + n2 + n3) { src = p; local = i - n1 - n2; }
  else return;
  f4 a = *(const f4*)(src + local);
  f4 b = *(const f4*)(src + local + 4);
  u16x8 o;
  o[0] = f2bf(a.x); o[1] = f2bf(a.y); o[2] = f2bf(a.z); o[3] = f2bf(a.w);
  o[4] = f2bf(b.x); o[5] = f2bf(b.y); o[6] = f2bf(b.z); o[7] = f2bf(b.w);
  *(u16x8*)(dst + i) = o;
}

// ================= 128^2 2-phase mainloop (gemm12, proven R14/R16) ==========
// C += A @ B^T with 32x32x16 MFMA. 16B-chunk XOR swizzle (0 bank conflicts).
// Wave grid 2x2 (256 thr): wave covers 64x64 = 2x2 acc tiles of 32x32.

__device__ __forceinline__ void stage_tile(
    const u16* __restrict__ A, const u16* __restrict__ B, int K,
    int k0, int tid, u16* L) {
  constexpr int TM = 128, TN = 128;
  const int wave = tid >> 6;
  #pragma unroll
  for (int it = 0; it < TM / 32; ++it) {
    int c = it * 256 + tid;            // chunk index = LDS position
    int row = c >> 3, pc = c & 7;
    int gc = pc ^ (row & 7);           // which global 16B chunk lands here
    async_cp16(A + (size_t)row * K + (k0 + gc * 8),
               &L[(it * 256 + wave * 64) * 8]);
  }
  #pragma unroll
  for (int it = 0; it < TN / 32; ++it) {
    int c = it * 256 + tid;
    int row = c >> 3, pc = c & 7;
    int gc = pc ^ (row & 7);
    async_cp16(B + (size_t)row * K + (k0 + gc * 8),
               &L[TM * 64 + (it * 256 + wave * 64) * 8]);
  }
}

__device__ __forceinline__ void compute_tile(
    const u16* L, int lane, int wrow, int wcol, f32x16 (&acc)[2][2]) {
  constexpr int TM = 128;
  #pragma unroll
  for (int s = 0; s < 4; ++s) {        // 4 k-steps of K=16
    const int h = s * 2 + (lane >> 5); // 16B chunk along K this lane needs
    bf16x8 bfr[2], afr[2];
    #pragma unroll
    for (int j = 0; j < 2; ++j) {
      const int rb = wcol * 64 + j * 32 + (lane & 31);
      bfr[j] = *(const bf16x8*)&L[TM * 64 + (rb * 8 + (h ^ (rb & 7))) * 8];
    }
    #pragma unroll
    for (int i = 0; i < 2; ++i) {
      const int ra = wrow * 64 + i * 32 + (lane & 31);
      afr[i] = *(const bf16x8*)&L[(ra * 8 + (h ^ (ra & 7))) * 8];
    }
    #pragma unroll
    for (int i = 0; i < 2; ++i)
      #pragma unroll
      for (int j = 0; j < 2; ++j)
        acc[i][j] = __builtin_amdgcn_mfma_f32_32x32x16_bf16(
            afr[i], bfr[j], acc[i][j], 0, 0, 0);
  }
}

__device__ __forceinline__ void mainloop(
    const u16* __restrict__ A, const u16* __restrict__ B, int K,
    int kbeg, int kend, int tid, u16* lds, f32x16 (&acc)[2][2]) {
  constexpr int BK = 64;
  constexpr int BUF = 16384;           // u16 per LDS buffer (32 KiB)
  const int lane = tid & 63;
  const int wave = tid >> 6;
  const int wrow = wave >> 1, wcol = wave & 1;

  stage_tile(A, B, K, kbeg, tid, lds); // prologue: tile 0 -> buf 0
  int cur = 0;
  for (int k0 = kbeg; k0 < kend; k0 += BK) {
    if (k0 + BK < kend) {
      stage_tile(A, B, K, k0 + BK, tid, lds + (cur ^ 1) * BUF);
      asm volatile("s_waitcnt vmcnt(8)" ::: "memory");
    } else {
      asm volatile("s_waitcnt vmcnt(0)" ::: "memory");
    }
    __builtin_amdgcn_s_barrier();      // all waves: current buffer complete
    compute_tile(lds + cur * BUF, lane, wrow, wcol, acc);
    __builtin_amdgcn_s_barrier();      // all waves done reading before next
    cur ^= 1;                          // iter overwrites this buffer
  }
}

// ================= 256^2 2-phase mainloop (gemm3, new this round) ===========
// 512 threads, 8 waves in 2x4 grid: wave covers 128x64 = 4x2 acc tiles.
// Same barrier/waitcnt skeleton; same 16B-chunk XOR swizzle; same 8
// global_load_lds per thread per tile (so vmcnt(8) count carries over).

__device__ __forceinline__ void stage_tile256(
    const u16* __restrict__ A, const u16* __restrict__ B, int K,
    int k0, int tid, u16* L) {
  const int wave = tid >> 6;
  #pragma unroll
  for (int it = 0; it < 4; ++it) {     // A: 256 rows x 8 chunks = 2048
    int c = it * 512 + tid;
    int row = c >> 3, pc = c & 7;
    int gc = pc ^ (row & 7);
    async_cp16(A + (size_t)row * K + (k0 + gc * 8),
               &L[(it * 512 + wave * 64) * 8]);
  }
  #pragma unroll
  for (int it = 0; it < 4; ++it) {     // B: 256 rows x 8 chunks
    int c = it * 512 + tid;
    int row = c >> 3, pc = c & 7;
    int gc = pc ^ (row & 7);
    async_cp16(B + (size_t)row * K + (k0 + gc * 8),
               &L[16384 + (it * 512 + wave * 64) * 8]);
  }
}

__device__ __forceinline__ void compute_tile256(
    const u16* L, int lane, int wrow, int wcol, f32x16 (&acc)[4][2]) {
  #pragma unroll
  for (int s = 0; s < 4; ++s) {        // 4 k-steps of K=16
    const int h = s * 2 + (lane >> 5);
    bf16x8 bfr[2], afr[4];
    #pragma unroll
    for (int j = 0; j < 2; ++j) {
      const int rb = wcol * 64 + j * 32 + (lane & 31);
      bfr[j] = *(const bf16x8*)&L[16384 + (rb * 8 + (h ^ (rb & 7))) * 8];
    }
    #pragma unroll
    for (int i = 0; i < 4; ++i) {
      const int ra = wrow * 128 + i * 32 + (lane & 31);
      afr[i] = *(const bf16x8*)&L[(ra * 8 + (h ^ (ra & 7))) * 8];
    }
    #pragma unroll
    for (int i = 0; i < 4; ++i)
      #pragma unroll
      for (int j = 0; j < 2; ++j)
        acc[i][j] = __builtin_amdgcn_mfma_f32_32x32x16_bf16(
            afr[i], bfr[j], acc[i][j], 0, 0, 0);
  }
}

__device__ __forceinline__ void mainloop256(
    const u16* __restrict__ A, const u16* __restrict__ B, int K,
    int kbeg, int kend, int tid, u16* lds, f32x16 (&acc)[4][2]) {
  constexpr int BK = 64;
  constexpr int BUF = 32768;           // u16 per LDS buffer (64 KiB)
  const int lane = tid & 63;
  const int wave = tid >> 6;
  const int wrow = wave >> 2, wcol = wave & 3;

  stage_tile256(A, B, K, kbeg, tid, lds);
  int cur = 0;
  for (int k0 = kbeg; k0 < kend; k0 += BK) {
    if (k0 + BK < kend) {
      stage_tile256(A, B, K, k0 + BK, tid, lds + (cur ^ 1) * BUF);
      asm volatile("s_waitcnt vmcnt(8)" ::: "memory");
    } else {
      asm volatile("s_waitcnt vmcnt(0)" ::: "memory");
    }
    __builtin_amdgcn_s_barrier();
    compute_tile256(lds + cur * BUF, lane, wrow, wcol, acc);
    __builtin_amdgcn_s_barrier();
    cur ^= 1;
  }
}

// 32x32 C/D mapping (m74/m101 verified): col = lane&31,
// row = (reg&3) + 8*(reg>>2) + 4*(lane>>5), reg in [0,16).

// ---- GEMM1+GEMM2 merged: [x; proto](4608 x 1024) @ feat^T, tile 128x128 ----
// 1D grid 576; XCD-supertile decode (9x8 panel per XCD). UNCHANGED from R16.
__global__ __launch_bounds__(256) void gemm12(
    const u16* __restrict__ xb, const u16* __restrict__ pb,
    const u16* __restrict__ fb, u16* __restrict__ Acat, u16* __restrict__ Bcat,
    const float* __restrict__ alpha, const float* __restrict__ beta,
    const float* __restrict__ theta) {
  constexpr int TM = 128, K = 1024, N = 2048;
  constexpr int TSTRIDE = 136;           // u16; 272B rows = 17*16B aligned
  __shared__ u16 lds[32768];             // 64 KiB: 2 mainloop bufs; transpose reuses

  const int tid = threadIdx.x;
  const int lane = tid & 63;
  const int wave = tid >> 6;
  const int wrow = wave >> 1, wcol = wave & 1;

  // XCD-aware supertile decode (bijective: 576 = 8 * 72, panels 9x8)
  const int bid = blockIdx.x;
  const int xcd = bid & 7, slot = bid >> 3;        // xcd 0..7, slot 0..71
  const int xt = (xcd & 3) * 9 + (slot >> 3);      // 0..35
  const int yt = (xcd >> 2) * 8 + (slot & 7);      // 0..15

  const int bm_all = xt * TM;
  const int bn = yt * 128;
  const bool is_x = bm_all < 4096;       // block purely x or proto (4096%128==0)
  const u16* A = is_x ? xb + (size_t)bm_all * K : pb + (size_t)(bm_all - 4096) * K;
  const u16* B = fb + (size_t)bn * K;

  f32x16 acc[2][2] = {};
  mainloop(A, B, K, 0, K, tid, lds, acc);

  float th = 0.f, al = 0.f, be = 0.f;
  if (!is_x) { th = theta[0]; al = alpha[0]; be = beta[0]; }
  u16* dst = is_x ? Acat : Bcat;
  const int rowbase = is_x ? bm_all : bm_all - 4096;
  const int rquad = 4 * (lane >> 5);

  #pragma unroll
  for (int half = 0; half < 2; ++half) {
    __syncthreads();   // protect lds reuse (mainloop end / previous half's reads)
    #pragma unroll
    for (int i = 0; i < 2; ++i) {
      #pragma unroll
      for (int j = 0; j < 2; ++j) {
        const int cl = wcol * 64 + j * 32 + (lane & 31);
        #pragma unroll
        for (int r = 0; r < 16; ++r) {
          const int rl = wrow * 64 + i * 32 + (r & 3) + 8 * (r >> 2) + rquad;
          float v = acc[i][j][r];
          float pres = v > 0.f ? v : 0.f;
          float o;
          if (is_x) o = half == 0 ? v * pres : 1.f - pres;
          else {
            float cc = v * pres;
            o = half == 0 ? th * cc - al * (1.f - pres) : -be * cc;
          }
          lds[rl * TSTRIDE + cl] = f2bf(o);
        }
      }
    }
    __syncthreads();
    #pragma unroll
    for (int v = 0; v < 8; ++v) {
      const int rl = v * 16 + (tid >> 4);
      const int c8 = (tid & 15) * 8;
      u16x8 vec = *(const u16x8*)&lds[rl * TSTRIDE + c8];
      *(u16x8*)&dst[(size_t)(rowbase + rl) * (2 * N) + bn + c8 + half * N] = vec;
    }
  }
}

// ---- GEMM3 split-K: part[z] = Acat @ Bcat^T partial (bf16), tile 256x256 ----
// KSPLIT=8, 1D grid 256 = 1 block/CU (256^2 template design point), 512 thr.
// z-slice = XCD (bid%8): per-XCD A working set = 4096x512x2B = 4MB = L2.
// slot = bid/8 (0..31): bxt = slot%16 (M tiles), byt = slot/16 (N tiles).
// Partials bf16 thread-linear: tile = 65536 u16; chunk q = i*4+j*2+h (0..15),
// 4096 u16 each.
__global__ __launch_bounds__(512) void gemm3(
    const u16* __restrict__ Acat, const u16* __restrict__ Bcat,
    u16* __restrict__ part) {
  constexpr int K = 4096, KSPLIT = 8;
  __shared__ u16 lds[65536];             // 128 KiB: 2 x 64 KiB buffers

  const int tid = threadIdx.x;
  const int bid = blockIdx.x;
  const int bz = bid & 7;                          // z-slice = XCD
  const int slot = bid >> 3;                       // 0..31
  const int bxt = slot & 15;                       // 0..15
  const int byt = slot >> 4;                       // 0..1

  const int bm = bxt * 256;
  const int bn = byt * 256;
  const int kbeg = bz * (K / KSPLIT);
  const int kend = kbeg + (K / KSPLIT);

  f32x16 acc[4][2] = {};
  mainloop256(Acat + (size_t)bm * K, Bcat + (size_t)bn * K, K, kbeg, kend,
              tid, lds, acc);

  const int tileId = byt * 16 + bxt;               // 0..31
  const size_t pbase = ((size_t)bz * 32 + tileId) * 65536;
  #pragma unroll
  for (int i = 0; i < 4; ++i)
    #pragma unroll
    for (int j = 0; j < 2; ++j)
      #pragma unroll
      for (int h = 0; h < 2; ++h) {
        u16x8 o;
        #pragma unroll
        for (int e = 0; e < 8; ++e) o[e] = f2bf(acc[i][j][h * 8 + e]);
        *(u16x8*)&part[pbase + (size_t)(i * 4 + j * 2 + h) * 4096 + tid * 8] = o;
      }
}

// ---- reduce bf16 partials over z=0..8, scatter fp32 to out ----
// 512 blocks x 512 thr: one q-chunk per block (tileId = bid>>4, q = bid&15).
// Mirrors gemm3 256^2 map: q = i*4+j*2+h; reg = h*8+e; wave 2x4 grid:
// row = bm + (wave>>2)*128 + i*32 + (reg&3)+8*(reg>>2)+4*(lane>>5);
// col = bn + (wave&3)*64 + j*32 + (lane&31).
__global__ __launch_bounds__(512) void reduce4(
    const u16* __restrict__ part, float* __restrict__ out) {
  constexpr int N = 512;
  const int tid = threadIdx.x;
  const int lane = tid & 63;
  const int wave = tid >> 6;
  const int wrow = wave >> 2, wcol = wave & 3;
  const int tileId = blockIdx.x >> 4;      // 0..31 = byt*16+bxt
  const int q = blockIdx.x & 15;
  const int bm = (tileId & 15) * 256;
  const int bn = (tileId >> 4) * 256;

  float v[8] = {};
  #pragma unroll
  for (int z = 0; z < 8; ++z) {
    u16x8 u = *(const u16x8*)&part[((size_t)z * 32 + tileId) * 65536 +
                                   (size_t)q * 4096 + tid * 8];
    #pragma unroll
    for (int e = 0; e < 8; ++e) v[e] += bf2f(u[e]);
  }
  const int i = q >> 2, j = (q >> 1) & 1, h = q & 1;
  const int gc = bn + wcol * 64 + j * 32 + (lane & 31);
  const int grb = bm + wrow * 128 + i * 32 + 4 * (lane >> 5);
  #pragma unroll
  for (int e = 0; e < 8; ++e) {
    const int reg = h * 8 + e;
    out[(size_t)(grb + (reg & 3) + 8 * (reg >> 2)) * N + gc] = v[e];
  }
}

extern "C" void kernel_launch(void* const* d_in, const int* in_sizes, int n_in,
                              void* d_out, int out_size, void* d_ws, size_t ws_size,
                              hipStream_t stream) {
  const float* x     = (const float*)d_in[0];
  const float* feat  = (const float*)d_in[1];
  const float* proto = (const float*)d_in[2];
  const float* alpha = (const float*)d_in[3];
  const float* beta  = (const float*)d_in[4];
  const float* theta = (const float*)d_in[5];
  float* out = (float*)d_out;

  constexpr int Bb = 4096, Ii = 1024, Pp = 512, Ff = 2048;

  // ws layout (NO aliasing — R12 defensive change): casts | Acat | Bcat | part.
  // Total ~105 MB of the 256 MiB workspace.
  char* ws = (char*)d_ws;
  u16* xb   = (u16*)ws;                               // 8.4 MB
  u16* fb   = xb + (size_t)Bb * Ii;                   // 4.2 MB
  u16* pb   = fb + (size_t)Ff * Ii;                   // 1.0 MB
  size_t r0 = 33554432;                               // 32 MiB region0 (casts)
  u16* Acat = (u16*)(ws + r0);                        // 33.6 MB
  u16* Bcat = Acat + (size_t)Bb * 2 * Ff;             // 4.2 MB
  u16* part = Bcat + (size_t)Pp * 2 * Ff;             // 33.6 MB (KSPLIT=8)

  const int n1 = Bb * Ii, n2 = Ff * Ii, n3 = Pp * Ii;
  cast3<<<((n1 + n2 + n3) / 8 + 255) / 256, 256, 0, stream>>>(
      x, feat, proto, xb, n1, n2, n3);

  // merged GEMM1+GEMM2: M=4608, N=2048; 1D grid 576 with XCD supertile decode
  gemm12<<<576, 256, 0, stream>>>(xb, pb, fb, Acat, Bcat, alpha, beta, theta);

  // GEMM3: 4096x512, K=4096 split 8 ways; 256^2 tile, grid 256 (1 blk/CU)
  gemm3<<<256, 512, 0, stream>>>(Acat, Bcat, part);

  // reduce z=0..8 -> out (16 chunks per tile, one per block)
  reduce4<<<512, 512, 0, stream>>>(part, out);
}